// Round 3
// baseline (1147.939 us; speedup 1.0000x reference)
//
#include <hip/hip_runtime.h>

#define DD 64
#define TT 8192
#define KK 2048
#define NTROWS 65536

// d_out layout (float offsets), matching reference return order:
// xd[8*64*8192] | codes[65536] | commit[1] | k_new[131072] | k_sum_n[131072] | k_elem_n[2048]
#define OFF_CODES  4194304ull
#define OFF_COMMIT 4259840ull
#define OFF_KNEW   4259841ull
#define OFF_KSUM   4390913ull
#define OFF_KELEM  4521985ull

// numpy pairwise_sum replica for 64 contiguous elements of v*v:
// squares separately rounded; 8 accumulators sequential; fixed combine tree.
__device__ __forceinline__ float np_sumsq64(const float* v) {
  float r[8];
#pragma unroll
  for (int j = 0; j < 8; ++j) r[j] = __fmul_rn(v[j], v[j]);
#pragma unroll
  for (int i = 8; i < 64; i += 8) {
#pragma unroll
    for (int j = 0; j < 8; ++j)
      r[j] = __fadd_rn(r[j], __fmul_rn(v[i + j], v[i + j]));
  }
  return __fadd_rn(
      __fadd_rn(__fadd_rn(r[0], r[1]), __fadd_rn(r[2], r[3])),
      __fadd_rn(__fadd_rn(r[4], r[5]), __fadd_rn(r[6], r[7])));
}

// ---------------- prep: sk[c] = np.sum(k[c]*k[c]) in replicated fp32 ----------
__global__ __launch_bounds__(256) void vq_prep(const float* __restrict__ k,
                                               float* __restrict__ sk) {
  int c = blockIdx.x * 256 + threadIdx.x;
  if (c < KK) {
    float kr[DD];
    const float* kp = k + (size_t)c * DD;
#pragma unroll
    for (int d = 0; d < DD; ++d) kr[d] = kp[d];
    sk[c] = np_sumsq64(kr);
  }
}

// ---------------- main: np-fp32-replica argmin + epilogue ----------------
__global__ __launch_bounds__(256) void vq_main(
    const float* __restrict__ x, const float* __restrict__ k,
    const float* __restrict__ sk, float* __restrict__ out_xd,
    float* __restrict__ out_codes, float* __restrict__ commit_acc,
    float* __restrict__ sum_acc, float* __restrict__ cnt_acc) {
  const int lane = threadIdx.x & 63;
  const int wv = threadIdx.x >> 6;
  const int gw = blockIdx.x * 4 + wv;
  const int r = lane & 15;               // row within wave
  const int q = lane >> 4;               // K-quarter

  const int R0 = gw * 16;
  const int n = R0 >> 13;                // T = 8192
  const int t = (R0 & (TT - 1)) + r;

  const float* xp = x + (size_t)n * (DD * TT) + t;

  float xr[DD];
#pragma unroll
  for (int d = 0; d < DD; ++d) xr[d] = xp[(size_t)d * TT];

  const float sumx = np_sumsq64(xr);     // np's ||x||^2, bit-exact

  // dist[c] = (sumx - 2*mm[c]) + sk[c]; mm = sequential-FMA dot (BLAS model)
  float best = 3.402823466e38f;
  int bidx = 0;
  const int c0 = q * (KK / 4);
  for (int cc = 0; cc < KK / 4; cc += 2) {
    const int cA = c0 + cc;
    const int cB = cA + 1;
    const float4* kpA = (const float4*)(k + (size_t)cA * DD);
    const float4* kpB = kpA + 16;
    float aA = 0.f, aB = 0.f;
#pragma unroll
    for (int i = 0; i < 16; ++i) {
      float4 kvA = kpA[i];
      float4 kvB = kpB[i];
      aA = fmaf(xr[4 * i + 0], kvA.x, aA);
      aB = fmaf(xr[4 * i + 0], kvB.x, aB);
      aA = fmaf(xr[4 * i + 1], kvA.y, aA);
      aB = fmaf(xr[4 * i + 1], kvB.y, aB);
      aA = fmaf(xr[4 * i + 2], kvA.z, aA);
      aB = fmaf(xr[4 * i + 2], kvB.z, aB);
      aA = fmaf(xr[4 * i + 3], kvA.w, aA);
      aB = fmaf(xr[4 * i + 3], kvB.w, aB);
    }
    const float dA = __fadd_rn(__fsub_rn(sumx, __fmul_rn(2.0f, aA)), sk[cA]);
    const float dB = __fadd_rn(__fsub_rn(sumx, __fmul_rn(2.0f, aB)), sk[cB]);
    if (dA < best) { best = dA; bidx = cA; }   // strict < -> first index wins
    if (dB < best) { best = dB; bidx = cB; }
  }

  // combine 4 quarters; tie -> lowest index (matches np.argmin)
  {
    float ov = __shfl_xor(best, 16);
    int oi = __shfl_xor(bidx, 16);
    if (ov < best || (ov == best && oi < bidx)) { best = ov; bidx = oi; }
    ov = __shfl_xor(best, 32);
    oi = __shfl_xor(bidx, 32);
    if (ov < best || (ov == best && oi < bidx)) { best = ov; bidx = oi; }
  }

  if (q == 0) {
    out_codes[R0 + r] = (float)bidx;
    atomicAdd(&cnt_acc[bidx], 1.0f);
  }

  // epilogue: lane (q,r) handles d = 4*dg + q
  float csum = 0.f;
  const float* krow = k + (size_t)bidx * DD;
  float* xd_base = out_xd + (size_t)n * (DD * TT) + t;
#pragma unroll
  for (int dg = 0; dg < 16; ++dg) {
    const int d = dg * 4 + q;
    const float xq = krow[d];
    const float xv = xp[(size_t)d * TT];
    const float diff = __fsub_rn(xq, xv);
    xd_base[(size_t)d * TT] = __fadd_rn(xv, diff);
    csum = fmaf(diff, diff, csum);
    atomicAdd(&sum_acc[(size_t)bidx * DD + d], xv);
  }

#pragma unroll
  for (int off = 32; off >= 1; off >>= 1) csum += __shfl_xor(csum, off);
  if (lane == 0) atomicAdd(commit_acc, csum);
}

// ---------------- finalize: EMA buffers, k_new, commit mean ----------------
__global__ __launch_bounds__(256) void vq_finalize(
    const float* __restrict__ k, const float* __restrict__ k_sum,
    const float* __restrict__ k_elem, const float* __restrict__ cnt_raw,
    float* __restrict__ out_commit, float* __restrict__ out_knew,
    float* __restrict__ out_ksum, float* __restrict__ out_kelem) {
  const int i = blockIdx.x * 256 + threadIdx.x;
  if (i == 0) {
    out_commit[0] = out_commit[0] / 4194304.0f;
  }
  if (i < KK * DD) {
    const int c = i >> 6;
    const float cnt = cnt_raw[c];
    // separately-rounded mul/mul/add matches np; exact 1.0f at cnt==1 boundary
    const float ke_n = __fadd_rn(__fmul_rn(0.99f, k_elem[c]), __fmul_rn(0.01f, cnt));
    const float s_raw = out_ksum[i];
    const float ks_n = __fadd_rn(__fmul_rn(0.99f, k_sum[i]), __fmul_rn(0.01f, s_raw));
    out_ksum[i] = ks_n;
    out_knew[i] = (ke_n >= 1.0f) ? (ks_n / ke_n) : k[i];
    if ((i & 63) == 0) out_kelem[c] = ke_n;
  }
}

extern "C" void kernel_launch(void* const* d_in, const int* in_sizes, int n_in,
                              void* d_out, int out_size, void* d_ws, size_t ws_size,
                              hipStream_t stream) {
  const float* x = (const float*)d_in[0];
  const float* k = (const float*)d_in[1];
  const float* k_sum = (const float*)d_in[2];
  const float* k_elem = (const float*)d_in[3];

  float* out = (float*)d_out;
  float* out_xd = out;
  float* out_codes = out + OFF_CODES;
  float* out_commit = out + OFF_COMMIT;
  float* out_knew = out + OFF_KNEW;
  float* out_ksum = out + OFF_KSUM;    // raw sum accumulator, finalized in place
  float* out_kelem = out + OFF_KELEM;

  char* ws = (char*)d_ws;
  float* sk = (float*)ws;              // 8 KB
  float* cnt_raw = (float*)(ws + 8192);

  hipMemsetAsync(out_ksum, 0, (size_t)KK * DD * sizeof(float), stream);
  hipMemsetAsync(cnt_raw, 0, (size_t)KK * sizeof(float), stream);
  hipMemsetAsync(out_commit, 0, sizeof(float), stream);

  vq_prep<<<(KK + 255) / 256, 256, 0, stream>>>(k, sk);

  vq_main<<<NTROWS / 64, 256, 0, stream>>>(x, k, sk, out_xd, out_codes,
                                           out_commit, out_ksum, cnt_raw);

  vq_finalize<<<(KK * DD + 255) / 256, 256, 0, stream>>>(
      k, k_sum, k_elem, cnt_raw, out_commit, out_knew, out_ksum, out_kelem);
}

// Round 4
// 1147.508 us; speedup vs baseline: 1.0004x; 1.0004x over previous
//
#include <hip/hip_runtime.h>

#define DD 64
#define TT 8192
#define KK 2048
#define NTROWS 65536

// d_out layout (float offsets), matching reference return order:
// xd[8*64*8192] | codes[65536] | commit[1] | k_new[131072] | k_sum_n[131072] | k_elem_n[2048]
#define OFF_CODES  4194304ull
#define OFF_COMMIT 4259840ull
#define OFF_KNEW   4259841ull
#define OFF_KSUM   4390913ull
#define OFF_KELEM  4521985ull

#define SQ(a) __fmul_rn((a), (a))
// numpy pairwise fold: sequential left-fold of 8 squared terms (stride 8)
#define FOLD8(a,b,c,d,e,f,g,h)                                              \
  __fadd_rn(__fadd_rn(__fadd_rn(__fadd_rn(__fadd_rn(__fadd_rn(__fadd_rn(    \
      SQ(a), SQ(b)), SQ(c)), SQ(d)), SQ(e)), SQ(f)), SQ(g)), SQ(h))

// ---------------- prep: sk[c] = np.sum(k[c]*k[c]) in replicated fp32 ----------
__global__ __launch_bounds__(256) void vq_prep(const float* __restrict__ k,
                                               float* __restrict__ sk) {
  int c = blockIdx.x * 256 + threadIdx.x;
  if (c < KK) {
    const float* v = k + (size_t)c * DD;
    float r[8];
#pragma unroll
    for (int j = 0; j < 8; ++j) r[j] = SQ(v[j]);
#pragma unroll
    for (int i = 8; i < 64; i += 8) {
#pragma unroll
      for (int j = 0; j < 8; ++j) r[j] = __fadd_rn(r[j], SQ(v[i + j]));
    }
    sk[c] = __fadd_rn(
        __fadd_rn(__fadd_rn(r[0], r[1]), __fadd_rn(r[2], r[3])),
        __fadd_rn(__fadd_rn(r[4], r[5]), __fadd_rn(r[6], r[7])));
  }
}

// ---------------- main: np-fp32-replica argmin + epilogue ----------------
__global__ __launch_bounds__(256) void vq_main(
    const float* __restrict__ x, const float* __restrict__ k,
    const float* __restrict__ sk, float* __restrict__ out_xd,
    float* __restrict__ out_codes, float* __restrict__ commit_acc,
    float* __restrict__ sum_acc, float* __restrict__ cnt_acc) {
  const int lane = threadIdx.x & 63;
  const int wv = threadIdx.x >> 6;
  const int gw = blockIdx.x * 4 + wv;
  const int r = lane & 15;               // row within wave
  const int q = lane >> 4;               // K-quarter

  const int R0 = gw * 16;
  const int n = R0 >> 13;                // T = 8192
  const int t = (R0 & (TT - 1)) + r;

  const float* xp = x + (size_t)n * (DD * TT) + t;

  // x row in 16 named float4s — no array, no address-taking -> guaranteed VGPRs
#define LDX(I)                                                   \
  make_float4(xp[(size_t)(4 * I + 0) * TT], xp[(size_t)(4 * I + 1) * TT], \
              xp[(size_t)(4 * I + 2) * TT], xp[(size_t)(4 * I + 3) * TT])
  const float4 x0 = LDX(0),  x1 = LDX(1),  x2 = LDX(2),  x3 = LDX(3);
  const float4 x4 = LDX(4),  x5 = LDX(5),  x6 = LDX(6),  x7 = LDX(7);
  const float4 x8 = LDX(8),  x9 = LDX(9),  x10 = LDX(10), x11 = LDX(11);
  const float4 x12 = LDX(12), x13 = LDX(13), x14 = LDX(14), x15 = LDX(15);
#undef LDX

  // np's ||x||^2: 8 accumulators over stride-8 elements, fixed fold tree
  const float r0 = FOLD8(x0.x, x2.x, x4.x, x6.x, x8.x, x10.x, x12.x, x14.x);
  const float r1 = FOLD8(x0.y, x2.y, x4.y, x6.y, x8.y, x10.y, x12.y, x14.y);
  const float r2 = FOLD8(x0.z, x2.z, x4.z, x6.z, x8.z, x10.z, x12.z, x14.z);
  const float r3 = FOLD8(x0.w, x2.w, x4.w, x6.w, x8.w, x10.w, x12.w, x14.w);
  const float r4 = FOLD8(x1.x, x3.x, x5.x, x7.x, x9.x, x11.x, x13.x, x15.x);
  const float r5 = FOLD8(x1.y, x3.y, x5.y, x7.y, x9.y, x11.y, x13.y, x15.y);
  const float r6 = FOLD8(x1.z, x3.z, x5.z, x7.z, x9.z, x11.z, x13.z, x15.z);
  const float r7 = FOLD8(x1.w, x3.w, x5.w, x7.w, x9.w, x11.w, x13.w, x15.w);
  const float sumx = __fadd_rn(
      __fadd_rn(__fadd_rn(r0, r1), __fadd_rn(r2, r3)),
      __fadd_rn(__fadd_rn(r4, r5), __fadd_rn(r6, r7)));

  // dist[c] = (sumx - 2*mm[c]) + sk[c]; mm = sequential-FMA dot over d=0..63
  float best = 3.402823466e38f;
  int bidx = 0;
  const int c0 = q * (KK / 4);
  for (int cc = 0; cc < KK / 4; cc += 2) {
    const int cA = c0 + cc;
    const int cB = cA + 1;
    const float4* kpA = (const float4*)(k + (size_t)cA * DD);
    const float4* kpB = kpA + 16;
    float aA = 0.f, aB = 0.f;
#define STEP(I, XV)                       \
    {                                     \
      const float4 kvA = kpA[I];          \
      const float4 kvB = kpB[I];          \
      aA = fmaf((XV).x, kvA.x, aA);       \
      aB = fmaf((XV).x, kvB.x, aB);       \
      aA = fmaf((XV).y, kvA.y, aA);       \
      aB = fmaf((XV).y, kvB.y, aB);       \
      aA = fmaf((XV).z, kvA.z, aA);       \
      aB = fmaf((XV).z, kvB.z, aB);       \
      aA = fmaf((XV).w, kvA.w, aA);       \
      aB = fmaf((XV).w, kvB.w, aB);       \
    }
    STEP(0, x0)   STEP(1, x1)   STEP(2, x2)   STEP(3, x3)
    STEP(4, x4)   STEP(5, x5)   STEP(6, x6)   STEP(7, x7)
    STEP(8, x8)   STEP(9, x9)   STEP(10, x10) STEP(11, x11)
    STEP(12, x12) STEP(13, x13) STEP(14, x14) STEP(15, x15)
#undef STEP
    const float dA = __fadd_rn(__fsub_rn(sumx, __fmul_rn(2.0f, aA)), sk[cA]);
    const float dB = __fadd_rn(__fsub_rn(sumx, __fmul_rn(2.0f, aB)), sk[cB]);
    if (dA < best) { best = dA; bidx = cA; }   // strict < -> first index wins
    if (dB < best) { best = dB; bidx = cB; }
  }

  // combine 4 quarters; tie -> lowest index (matches np.argmin)
  {
    float ov = __shfl_xor(best, 16);
    int oi = __shfl_xor(bidx, 16);
    if (ov < best || (ov == best && oi < bidx)) { best = ov; bidx = oi; }
    ov = __shfl_xor(best, 32);
    oi = __shfl_xor(bidx, 32);
    if (ov < best || (ov == best && oi < bidx)) { best = ov; bidx = oi; }
  }

  if (q == 0) {
    out_codes[R0 + r] = (float)bidx;
    atomicAdd(&cnt_acc[bidx], 1.0f);
  }

  // epilogue: lane (q,r) handles d = 4*dg + q (x reloaded; L1/L2-hot)
  float csum = 0.f;
  const float* krow = k + (size_t)bidx * DD;
  float* xd_base = out_xd + (size_t)n * (DD * TT) + t;
#pragma unroll
  for (int dg = 0; dg < 16; ++dg) {
    const int d = dg * 4 + q;
    const float xq = krow[d];
    const float xv = xp[(size_t)d * TT];
    const float diff = __fsub_rn(xq, xv);
    xd_base[(size_t)d * TT] = __fadd_rn(xv, diff);
    csum = fmaf(diff, diff, csum);
    atomicAdd(&sum_acc[(size_t)bidx * DD + d], xv);
  }

#pragma unroll
  for (int off = 32; off >= 1; off >>= 1) csum += __shfl_xor(csum, off);
  if (lane == 0) atomicAdd(commit_acc, csum);
}

// ---------------- finalize: EMA buffers, k_new, commit mean ----------------
__global__ __launch_bounds__(256) void vq_finalize(
    const float* __restrict__ k, const float* __restrict__ k_sum,
    const float* __restrict__ k_elem, const float* __restrict__ cnt_raw,
    float* __restrict__ out_commit, float* __restrict__ out_knew,
    float* __restrict__ out_ksum, float* __restrict__ out_kelem) {
  const int i = blockIdx.x * 256 + threadIdx.x;
  if (i == 0) {
    out_commit[0] = out_commit[0] / 4194304.0f;
  }
  if (i < KK * DD) {
    const int c = i >> 6;
    const float cnt = cnt_raw[c];
    const float ke_n = __fadd_rn(__fmul_rn(0.99f, k_elem[c]), __fmul_rn(0.01f, cnt));
    const float s_raw = out_ksum[i];
    const float ks_n = __fadd_rn(__fmul_rn(0.99f, k_sum[i]), __fmul_rn(0.01f, s_raw));
    out_ksum[i] = ks_n;
    out_knew[i] = (ke_n >= 1.0f) ? (ks_n / ke_n) : k[i];
    if ((i & 63) == 0) out_kelem[c] = ke_n;
  }
}

extern "C" void kernel_launch(void* const* d_in, const int* in_sizes, int n_in,
                              void* d_out, int out_size, void* d_ws, size_t ws_size,
                              hipStream_t stream) {
  const float* x = (const float*)d_in[0];
  const float* k = (const float*)d_in[1];
  const float* k_sum = (const float*)d_in[2];
  const float* k_elem = (const float*)d_in[3];

  float* out = (float*)d_out;
  float* out_xd = out;
  float* out_codes = out + OFF_CODES;
  float* out_commit = out + OFF_COMMIT;
  float* out_knew = out + OFF_KNEW;
  float* out_ksum = out + OFF_KSUM;    // raw sum accumulator, finalized in place
  float* out_kelem = out + OFF_KELEM;

  char* ws = (char*)d_ws;
  float* sk = (float*)ws;              // 8 KB
  float* cnt_raw = (float*)(ws + 8192);

  hipMemsetAsync(out_ksum, 0, (size_t)KK * DD * sizeof(float), stream);
  hipMemsetAsync(cnt_raw, 0, (size_t)KK * sizeof(float), stream);
  hipMemsetAsync(out_commit, 0, sizeof(float), stream);

  vq_prep<<<(KK + 255) / 256, 256, 0, stream>>>(k, sk);

  vq_main<<<NTROWS / 64, 256, 0, stream>>>(x, k, sk, out_xd, out_codes,
                                           out_commit, out_ksum, cnt_raw);

  vq_finalize<<<(KK * DD + 255) / 256, 256, 0, stream>>>(
      k, k_sum, k_elem, cnt_raw, out_commit, out_knew, out_ksum, out_kelem);
}

// Round 5
// 1145.986 us; speedup vs baseline: 1.0017x; 1.0013x over previous
//
#include <hip/hip_runtime.h>

#define DD 64
#define TT 8192
#define KK 2048
#define NTROWS 65536

// d_out layout (float offsets), matching reference return order:
// xd[8*64*8192] | codes[65536] | commit[1] | k_new[131072] | k_sum_n[131072] | k_elem_n[2048]
#define OFF_CODES  4194304ull
#define OFF_COMMIT 4259840ull
#define OFF_KNEW   4259841ull
#define OFF_KSUM   4390913ull
#define OFF_KELEM  4521985ull

#define SQ(a) __fmul_rn((a), (a))
// numpy pairwise fold: sequential left-fold of 8 squared terms (stride 8)
#define FOLD8(a,b,c,d,e,f,g,h)                                              \
  __fadd_rn(__fadd_rn(__fadd_rn(__fadd_rn(__fadd_rn(__fadd_rn(__fadd_rn(    \
      SQ(a), SQ(b)), SQ(c)), SQ(d)), SQ(e)), SQ(f)), SQ(g)), SQ(h))

// ---------------- prep: sk[c] = np.sum(k[c]*k[c]) in replicated fp32 ----------
__global__ __launch_bounds__(256) void vq_prep(const float* __restrict__ k,
                                               float* __restrict__ sk) {
  int c = blockIdx.x * 256 + threadIdx.x;
  if (c < KK) {
    const float* v = k + (size_t)c * DD;
    float r[8];
#pragma unroll
    for (int j = 0; j < 8; ++j) r[j] = SQ(v[j]);
#pragma unroll
    for (int i = 8; i < 64; i += 8) {
#pragma unroll
      for (int j = 0; j < 8; ++j) r[j] = __fadd_rn(r[j], SQ(v[i + j]));
    }
    sk[c] = __fadd_rn(
        __fadd_rn(__fadd_rn(r[0], r[1]), __fadd_rn(r[2], r[3])),
        __fadd_rn(__fadd_rn(r[4], r[5]), __fadd_rn(r[6], r[7])));
  }
}

// ---------------- main: np-fp32-replica argmin + epilogue ----------------
// __launch_bounds__(256, 2): min 2 waves/EU -> VGPR cap 256. The default
// heuristic capped at 52 VGPRs and spilled the 64-float x row to scratch
// (round-4 counters: WRITE_SIZE 68 MB = 17 MB xd + 51 MB spill; VALUBusy 22%).
__global__ __launch_bounds__(256, 2) void vq_main(
    const float* __restrict__ x, const float* __restrict__ k,
    const float* __restrict__ sk, float* __restrict__ out_xd,
    float* __restrict__ out_codes, float* __restrict__ commit_acc,
    float* __restrict__ sum_acc, float* __restrict__ cnt_acc) {
  const int lane = threadIdx.x & 63;
  const int wv = threadIdx.x >> 6;
  const int gw = blockIdx.x * 4 + wv;
  const int r = lane & 15;               // row within wave
  const int q = lane >> 4;               // K-quarter

  const int R0 = gw * 16;
  const int n = R0 >> 13;                // T = 8192
  const int t = (R0 & (TT - 1)) + r;

  const float* xp = x + (size_t)n * (DD * TT) + t;

  // x row in 16 named float4s (kept in VGPRs now that the cap is 256)
#define LDX(I)                                                   \
  make_float4(xp[(size_t)(4 * I + 0) * TT], xp[(size_t)(4 * I + 1) * TT], \
              xp[(size_t)(4 * I + 2) * TT], xp[(size_t)(4 * I + 3) * TT])
  const float4 x0 = LDX(0),  x1 = LDX(1),  x2 = LDX(2),  x3 = LDX(3);
  const float4 x4 = LDX(4),  x5 = LDX(5),  x6 = LDX(6),  x7 = LDX(7);
  const float4 x8 = LDX(8),  x9 = LDX(9),  x10 = LDX(10), x11 = LDX(11);
  const float4 x12 = LDX(12), x13 = LDX(13), x14 = LDX(14), x15 = LDX(15);
#undef LDX

  // np's ||x||^2: 8 accumulators over stride-8 elements, fixed fold tree
  const float r0 = FOLD8(x0.x, x2.x, x4.x, x6.x, x8.x, x10.x, x12.x, x14.x);
  const float r1 = FOLD8(x0.y, x2.y, x4.y, x6.y, x8.y, x10.y, x12.y, x14.y);
  const float r2 = FOLD8(x0.z, x2.z, x4.z, x6.z, x8.z, x10.z, x12.z, x14.z);
  const float r3 = FOLD8(x0.w, x2.w, x4.w, x6.w, x8.w, x10.w, x12.w, x14.w);
  const float r4 = FOLD8(x1.x, x3.x, x5.x, x7.x, x9.x, x11.x, x13.x, x15.x);
  const float r5 = FOLD8(x1.y, x3.y, x5.y, x7.y, x9.y, x11.y, x13.y, x15.y);
  const float r6 = FOLD8(x1.z, x3.z, x5.z, x7.z, x9.z, x11.z, x13.z, x15.z);
  const float r7 = FOLD8(x1.w, x3.w, x5.w, x7.w, x9.w, x11.w, x13.w, x15.w);
  const float sumx = __fadd_rn(
      __fadd_rn(__fadd_rn(r0, r1), __fadd_rn(r2, r3)),
      __fadd_rn(__fadd_rn(r4, r5), __fadd_rn(r6, r7)));

  // dist[c] = (sumx - 2*mm[c]) + sk[c]; mm = sequential-FMA dot over d=0..63
  float best = 3.402823466e38f;
  int bidx = 0;
  const int c0 = q * (KK / 4);
  for (int cc = 0; cc < KK / 4; cc += 2) {
    const int cA = c0 + cc;
    const int cB = cA + 1;
    const float4* kpA = (const float4*)(k + (size_t)cA * DD);
    const float4* kpB = kpA + 16;
    float aA = 0.f, aB = 0.f;
#define STEP(I, XV)                       \
    {                                     \
      const float4 kvA = kpA[I];          \
      const float4 kvB = kpB[I];          \
      aA = fmaf((XV).x, kvA.x, aA);       \
      aB = fmaf((XV).x, kvB.x, aB);       \
      aA = fmaf((XV).y, kvA.y, aA);       \
      aB = fmaf((XV).y, kvB.y, aB);       \
      aA = fmaf((XV).z, kvA.z, aA);       \
      aB = fmaf((XV).z, kvB.z, aB);       \
      aA = fmaf((XV).w, kvA.w, aA);       \
      aB = fmaf((XV).w, kvB.w, aB);       \
    }
    STEP(0, x0)   STEP(1, x1)   STEP(2, x2)   STEP(3, x3)
    STEP(4, x4)   STEP(5, x5)   STEP(6, x6)   STEP(7, x7)
    STEP(8, x8)   STEP(9, x9)   STEP(10, x10) STEP(11, x11)
    STEP(12, x12) STEP(13, x13) STEP(14, x14) STEP(15, x15)
#undef STEP
    const float dA = __fadd_rn(__fsub_rn(sumx, __fmul_rn(2.0f, aA)), sk[cA]);
    const float dB = __fadd_rn(__fsub_rn(sumx, __fmul_rn(2.0f, aB)), sk[cB]);
    if (dA < best) { best = dA; bidx = cA; }   // strict < -> first index wins
    if (dB < best) { best = dB; bidx = cB; }
  }

  // combine 4 quarters; tie -> lowest index (matches np.argmin)
  {
    float ov = __shfl_xor(best, 16);
    int oi = __shfl_xor(bidx, 16);
    if (ov < best || (ov == best && oi < bidx)) { best = ov; bidx = oi; }
    ov = __shfl_xor(best, 32);
    oi = __shfl_xor(bidx, 32);
    if (ov < best || (ov == best && oi < bidx)) { best = ov; bidx = oi; }
  }

  if (q == 0) {
    out_codes[R0 + r] = (float)bidx;
    atomicAdd(&cnt_acc[bidx], 1.0f);
  }

  // epilogue: lane (q,r) handles d = 4*dg + q (x reloaded; L1/L2-hot)
  float csum = 0.f;
  const float* krow = k + (size_t)bidx * DD;
  float* xd_base = out_xd + (size_t)n * (DD * TT) + t;
#pragma unroll
  for (int dg = 0; dg < 16; ++dg) {
    const int d = dg * 4 + q;
    const float xq = krow[d];
    const float xv = xp[(size_t)d * TT];
    const float diff = __fsub_rn(xq, xv);
    xd_base[(size_t)d * TT] = __fadd_rn(xv, diff);
    csum = fmaf(diff, diff, csum);
    atomicAdd(&sum_acc[(size_t)bidx * DD + d], xv);
  }

#pragma unroll
  for (int off = 32; off >= 1; off >>= 1) csum += __shfl_xor(csum, off);
  if (lane == 0) atomicAdd(commit_acc, csum);
}

// ---------------- finalize: EMA buffers, k_new, commit mean ----------------
__global__ __launch_bounds__(256) void vq_finalize(
    const float* __restrict__ k, const float* __restrict__ k_sum,
    const float* __restrict__ k_elem, const float* __restrict__ cnt_raw,
    float* __restrict__ out_commit, float* __restrict__ out_knew,
    float* __restrict__ out_ksum, float* __restrict__ out_kelem) {
  const int i = blockIdx.x * 256 + threadIdx.x;
  if (i == 0) {
    out_commit[0] = out_commit[0] / 4194304.0f;
  }
  if (i < KK * DD) {
    const int c = i >> 6;
    const float cnt = cnt_raw[c];
    const float ke_n = __fadd_rn(__fmul_rn(0.99f, k_elem[c]), __fmul_rn(0.01f, cnt));
    const float s_raw = out_ksum[i];
    const float ks_n = __fadd_rn(__fmul_rn(0.99f, k_sum[i]), __fmul_rn(0.01f, s_raw));
    out_ksum[i] = ks_n;
    out_knew[i] = (ke_n >= 1.0f) ? (ks_n / ke_n) : k[i];
    if ((i & 63) == 0) out_kelem[c] = ke_n;
  }
}

extern "C" void kernel_launch(void* const* d_in, const int* in_sizes, int n_in,
                              void* d_out, int out_size, void* d_ws, size_t ws_size,
                              hipStream_t stream) {
  const float* x = (const float*)d_in[0];
  const float* k = (const float*)d_in[1];
  const float* k_sum = (const float*)d_in[2];
  const float* k_elem = (const float*)d_in[3];

  float* out = (float*)d_out;
  float* out_xd = out;
  float* out_codes = out + OFF_CODES;
  float* out_commit = out + OFF_COMMIT;
  float* out_knew = out + OFF_KNEW;
  float* out_ksum = out + OFF_KSUM;    // raw sum accumulator, finalized in place
  float* out_kelem = out + OFF_KELEM;

  char* ws = (char*)d_ws;
  float* sk = (float*)ws;              // 8 KB
  float* cnt_raw = (float*)(ws + 8192);

  hipMemsetAsync(out_ksum, 0, (size_t)KK * DD * sizeof(float), stream);
  hipMemsetAsync(cnt_raw, 0, (size_t)KK * sizeof(float), stream);
  hipMemsetAsync(out_commit, 0, sizeof(float), stream);

  vq_prep<<<(KK + 255) / 256, 256, 0, stream>>>(k, sk);

  vq_main<<<NTROWS / 64, 256, 0, stream>>>(x, k, sk, out_xd, out_codes,
                                           out_commit, out_ksum, cnt_raw);

  vq_finalize<<<(KK * DD + 255) / 256, 256, 0, stream>>>(
      k, k_sum, k_elem, cnt_raw, out_commit, out_knew, out_ksum, out_kelem);
}

// Round 6
// 1080.725 us; speedup vs baseline: 1.0622x; 1.0604x over previous
//
#include <hip/hip_runtime.h>

#define DD 64
#define TT 8192
#define KK 2048
#define NTROWS 65536

// d_out layout (float offsets), matching reference return order:
// xd[8*64*8192] | codes[65536] | commit[1] | k_new[131072] | k_sum_n[131072] | k_elem_n[2048]
#define OFF_CODES  4194304ull
#define OFF_COMMIT 4259840ull
#define OFF_KNEW   4259841ull
#define OFF_KSUM   4390913ull
#define OFF_KELEM  4521985ull

#define SQ(a) __fmul_rn((a), (a))
// numpy pairwise fold: sequential left-fold of 8 squared terms (stride 8)
#define FOLD8(a,b,c,d,e,f,g,h)                                              \
  __fadd_rn(__fadd_rn(__fadd_rn(__fadd_rn(__fadd_rn(__fadd_rn(__fadd_rn(    \
      SQ(a), SQ(b)), SQ(c)), SQ(d)), SQ(e)), SQ(f)), SQ(g)), SQ(h))

// ---------------- prep: sk[c] = np.sum(k[c]*k[c]) in replicated fp32 ----------
__global__ __launch_bounds__(256) void vq_prep(const float* __restrict__ k,
                                               float* __restrict__ sk) {
  int c = blockIdx.x * 256 + threadIdx.x;
  if (c < KK) {
    const float* v = k + (size_t)c * DD;
    float r[8];
#pragma unroll
    for (int j = 0; j < 8; ++j) r[j] = SQ(v[j]);
#pragma unroll
    for (int i = 8; i < 64; i += 8) {
#pragma unroll
      for (int j = 0; j < 8; ++j) r[j] = __fadd_rn(r[j], SQ(v[i + j]));
    }
    sk[c] = __fadd_rn(
        __fadd_rn(__fadd_rn(r[0], r[1]), __fadd_rn(r[2], r[3])),
        __fadd_rn(__fadd_rn(r[4], r[5]), __fadd_rn(r[6], r[7])));
  }
}

// ---------------- main: np-fp32-replica argmin + epilogue ----------------
// amdgpu_waves_per_eu(4,4): pin the scheduler to the 4-waves/EU tier ->
// 128-VGPR budget. launch_bounds(256,2) only set a MINIMUM occupancy (a reg
// CAP); the scheduler still pressure-squeezed to 52 VGPRs and spilled the
// 64-float x row to scratch (rounds 3-5: WRITE_SIZE 68 MB = 17 MB xd +
// 51 MB spill = ~49 floats/lane; VALUBusy 22%, latency-serialized loads).
__global__ __launch_bounds__(256)
__attribute__((amdgpu_waves_per_eu(4, 4)))
void vq_main(
    const float* __restrict__ x, const float* __restrict__ k,
    const float* __restrict__ sk, float* __restrict__ out_xd,
    float* __restrict__ out_codes, float* __restrict__ commit_acc,
    float* __restrict__ sum_acc, float* __restrict__ cnt_acc) {
  const int lane = threadIdx.x & 63;
  const int wv = threadIdx.x >> 6;
  const int gw = blockIdx.x * 4 + wv;
  const int r = lane & 15;               // row within wave
  const int q = lane >> 4;               // K-quarter

  const int R0 = gw * 16;
  const int n = R0 >> 13;                // T = 8192
  const int t = (R0 & (TT - 1)) + r;

  const float* xp = x + (size_t)n * (DD * TT) + t;

  // x row in 16 named float4s (held in VGPRs at the 128-reg tier)
#define LDX(I)                                                   \
  make_float4(xp[(size_t)(4 * I + 0) * TT], xp[(size_t)(4 * I + 1) * TT], \
              xp[(size_t)(4 * I + 2) * TT], xp[(size_t)(4 * I + 3) * TT])
  const float4 x0 = LDX(0),  x1 = LDX(1),  x2 = LDX(2),  x3 = LDX(3);
  const float4 x4 = LDX(4),  x5 = LDX(5),  x6 = LDX(6),  x7 = LDX(7);
  const float4 x8 = LDX(8),  x9 = LDX(9),  x10 = LDX(10), x11 = LDX(11);
  const float4 x12 = LDX(12), x13 = LDX(13), x14 = LDX(14), x15 = LDX(15);
#undef LDX

  // np's ||x||^2: 8 accumulators over stride-8 elements, fixed fold tree
  const float r0 = FOLD8(x0.x, x2.x, x4.x, x6.x, x8.x, x10.x, x12.x, x14.x);
  const float r1 = FOLD8(x0.y, x2.y, x4.y, x6.y, x8.y, x10.y, x12.y, x14.y);
  const float r2 = FOLD8(x0.z, x2.z, x4.z, x6.z, x8.z, x10.z, x12.z, x14.z);
  const float r3 = FOLD8(x0.w, x2.w, x4.w, x6.w, x8.w, x10.w, x12.w, x14.w);
  const float r4 = FOLD8(x1.x, x3.x, x5.x, x7.x, x9.x, x11.x, x13.x, x15.x);
  const float r5 = FOLD8(x1.y, x3.y, x5.y, x7.y, x9.y, x11.y, x13.y, x15.y);
  const float r6 = FOLD8(x1.z, x3.z, x5.z, x7.z, x9.z, x11.z, x13.z, x15.z);
  const float r7 = FOLD8(x1.w, x3.w, x5.w, x7.w, x9.w, x11.w, x13.w, x15.w);
  const float sumx = __fadd_rn(
      __fadd_rn(__fadd_rn(r0, r1), __fadd_rn(r2, r3)),
      __fadd_rn(__fadd_rn(r4, r5), __fadd_rn(r6, r7)));

  // dist[c] = (sumx - 2*mm[c]) + sk[c]; mm = sequential-FMA dot over d=0..63
  float best = 3.402823466e38f;
  int bidx = 0;
  const int c0 = q * (KK / 4);
  for (int cc = 0; cc < KK / 4; cc += 2) {
    const int cA = c0 + cc;
    const int cB = cA + 1;
    const float4* kpA = (const float4*)(k + (size_t)cA * DD);
    const float4* kpB = kpA + 16;
    float aA = 0.f, aB = 0.f;
#define STEP(I, XV)                       \
    {                                     \
      const float4 kvA = kpA[I];          \
      const float4 kvB = kpB[I];          \
      aA = fmaf((XV).x, kvA.x, aA);       \
      aB = fmaf((XV).x, kvB.x, aB);       \
      aA = fmaf((XV).y, kvA.y, aA);       \
      aB = fmaf((XV).y, kvB.y, aB);       \
      aA = fmaf((XV).z, kvA.z, aA);       \
      aB = fmaf((XV).z, kvB.z, aB);       \
      aA = fmaf((XV).w, kvA.w, aA);       \
      aB = fmaf((XV).w, kvB.w, aB);       \
    }
    STEP(0, x0)   STEP(1, x1)   STEP(2, x2)   STEP(3, x3)
    STEP(4, x4)   STEP(5, x5)   STEP(6, x6)   STEP(7, x7)
    STEP(8, x8)   STEP(9, x9)   STEP(10, x10) STEP(11, x11)
    STEP(12, x12) STEP(13, x13) STEP(14, x14) STEP(15, x15)
#undef STEP
    const float dA = __fadd_rn(__fsub_rn(sumx, __fmul_rn(2.0f, aA)), sk[cA]);
    const float dB = __fadd_rn(__fsub_rn(sumx, __fmul_rn(2.0f, aB)), sk[cB]);
    if (dA < best) { best = dA; bidx = cA; }   // strict < -> first index wins
    if (dB < best) { best = dB; bidx = cB; }
  }

  // combine 4 quarters; tie -> lowest index (matches np.argmin)
  {
    float ov = __shfl_xor(best, 16);
    int oi = __shfl_xor(bidx, 16);
    if (ov < best || (ov == best && oi < bidx)) { best = ov; bidx = oi; }
    ov = __shfl_xor(best, 32);
    oi = __shfl_xor(bidx, 32);
    if (ov < best || (ov == best && oi < bidx)) { best = ov; bidx = oi; }
  }

  if (q == 0) {
    out_codes[R0 + r] = (float)bidx;
    atomicAdd(&cnt_acc[bidx], 1.0f);
  }

  // epilogue: lane (q,r) handles d = 4*dg + q (x reloaded; L1/L2-hot)
  float csum = 0.f;
  const float* krow = k + (size_t)bidx * DD;
  float* xd_base = out_xd + (size_t)n * (DD * TT) + t;
#pragma unroll
  for (int dg = 0; dg < 16; ++dg) {
    const int d = dg * 4 + q;
    const float xq = krow[d];
    const float xv = xp[(size_t)d * TT];
    const float diff = __fsub_rn(xq, xv);
    xd_base[(size_t)d * TT] = __fadd_rn(xv, diff);
    csum = fmaf(diff, diff, csum);
    atomicAdd(&sum_acc[(size_t)bidx * DD + d], xv);
  }

#pragma unroll
  for (int off = 32; off >= 1; off >>= 1) csum += __shfl_xor(csum, off);
  if (lane == 0) atomicAdd(commit_acc, csum);
}

// ---------------- finalize: EMA buffers, k_new, commit mean ----------------
__global__ __launch_bounds__(256) void vq_finalize(
    const float* __restrict__ k, const float* __restrict__ k_sum,
    const float* __restrict__ k_elem, const float* __restrict__ cnt_raw,
    float* __restrict__ out_commit, float* __restrict__ out_knew,
    float* __restrict__ out_ksum, float* __restrict__ out_kelem) {
  const int i = blockIdx.x * 256 + threadIdx.x;
  if (i == 0) {
    out_commit[0] = out_commit[0] / 4194304.0f;
  }
  if (i < KK * DD) {
    const int c = i >> 6;
    const float cnt = cnt_raw[c];
    const float ke_n = __fadd_rn(__fmul_rn(0.99f, k_elem[c]), __fmul_rn(0.01f, cnt));
    const float s_raw = out_ksum[i];
    const float ks_n = __fadd_rn(__fmul_rn(0.99f, k_sum[i]), __fmul_rn(0.01f, s_raw));
    out_ksum[i] = ks_n;
    out_knew[i] = (ke_n >= 1.0f) ? (ks_n / ke_n) : k[i];
    if ((i & 63) == 0) out_kelem[c] = ke_n;
  }
}

extern "C" void kernel_launch(void* const* d_in, const int* in_sizes, int n_in,
                              void* d_out, int out_size, void* d_ws, size_t ws_size,
                              hipStream_t stream) {
  const float* x = (const float*)d_in[0];
  const float* k = (const float*)d_in[1];
  const float* k_sum = (const float*)d_in[2];
  const float* k_elem = (const float*)d_in[3];

  float* out = (float*)d_out;
  float* out_xd = out;
  float* out_codes = out + OFF_CODES;
  float* out_commit = out + OFF_COMMIT;
  float* out_knew = out + OFF_KNEW;
  float* out_ksum = out + OFF_KSUM;    // raw sum accumulator, finalized in place
  float* out_kelem = out + OFF_KELEM;

  char* ws = (char*)d_ws;
  float* sk = (float*)ws;              // 8 KB
  float* cnt_raw = (float*)(ws + 8192);

  hipMemsetAsync(out_ksum, 0, (size_t)KK * DD * sizeof(float), stream);
  hipMemsetAsync(cnt_raw, 0, (size_t)KK * sizeof(float), stream);
  hipMemsetAsync(out_commit, 0, sizeof(float), stream);

  vq_prep<<<(KK + 255) / 256, 256, 0, stream>>>(k, sk);

  vq_main<<<NTROWS / 64, 256, 0, stream>>>(x, k, sk, out_xd, out_codes,
                                           out_commit, out_ksum, cnt_raw);

  vq_finalize<<<(KK * DD + 255) / 256, 256, 0, stream>>>(
      k, k_sum, k_elem, cnt_raw, out_commit, out_knew, out_ksum, out_kelem);
}

// Round 7
// 1071.030 us; speedup vs baseline: 1.0718x; 1.0091x over previous
//
#include <hip/hip_runtime.h>

#define DD 64
#define TT 8192
#define KK 2048
#define NTROWS 65536

// d_out layout (float offsets), matching reference return order:
// xd[8*64*8192] | codes[65536] | commit[1] | k_new[131072] | k_sum_n[131072] | k_elem_n[2048]
#define OFF_CODES  4194304ull
#define OFF_COMMIT 4259840ull
#define OFF_KNEW   4259841ull
#define OFF_KSUM   4390913ull
#define OFF_KELEM  4521985ull

#define SQ(a) __fmul_rn((a), (a))

// ---------------- prep: sk[c] = np.sum(k[c]*k[c]) in replicated fp32 ----------
__global__ __launch_bounds__(256) void vq_prep(const float* __restrict__ k,
                                               float* __restrict__ sk) {
  int c = blockIdx.x * 256 + threadIdx.x;
  if (c < KK) {
    const float* v = k + (size_t)c * DD;
    float r[8];
#pragma unroll
    for (int j = 0; j < 8; ++j) r[j] = SQ(v[j]);
#pragma unroll
    for (int i = 8; i < 64; i += 8) {
#pragma unroll
      for (int j = 0; j < 8; ++j) r[j] = __fadd_rn(r[j], SQ(v[i + j]));
    }
    sk[c] = __fadd_rn(
        __fadd_rn(__fadd_rn(r[0], r[1]), __fadd_rn(r[2], r[3])),
        __fadd_rn(__fadd_rn(r[4], r[5]), __fadd_rn(r[6], r[7])));
  }
}

// ---------------- main: np-fp32-replica argmin + epilogue ----------------
// x row lives in LDS (padded [64][68]); the K-loop re-reads 16B chunks via
// ds_read_b128 per step. This caps loop register pressure at ~40 VGPRs so
// the allocator can't spill the x row to scratch (rounds 3-6: 52-60 VGPRs,
// ~51 MB one-time spill, FMA chain serialized on ~160-cyc scratch reloads).
__global__ __launch_bounds__(256)
__attribute__((amdgpu_waves_per_eu(4, 4)))
void vq_main(
    const float* __restrict__ x, const float* __restrict__ k,
    const float* __restrict__ sk, float* __restrict__ out_xd,
    float* __restrict__ out_codes, float* __restrict__ commit_acc,
    float* __restrict__ sum_acc, float* __restrict__ cnt_acc) {
  __shared__ float xs[64][68];           // 64 rows x 64 d, +4 pad (17408 B)

  const int lane = threadIdx.x & 63;
  const int wv = threadIdx.x >> 6;
  const int gw = blockIdx.x * 4 + wv;
  const int r = lane & 15;               // row within wave
  const int q = lane >> 4;               // K-quarter

  const int R0 = gw * 16;
  const int n = R0 >> 13;                // T = 8192
  const int t = (R0 & (TT - 1)) + r;

  // ---- stage block's 64 rows (consecutive t, one n) into LDS, coalesced ----
  {
    const int bt = (blockIdx.x * 64) & (TT - 1);
    const float* xb = x + (size_t)n * (DD * TT) + bt;
    const int tt = threadIdx.x & 63;
    const int dq = threadIdx.x >> 6;     // 0..3
#pragma unroll
    for (int chunk = 0; chunk < 16; ++chunk) {
      const int d = chunk * 4 + dq;
      xs[tt][d] = xb[(size_t)d * TT + tt];
    }
  }
  __syncthreads();

  const int row = wv * 16 + r;           // this lane's row in xs
  const float* xp = x + (size_t)n * (DD * TT) + t;  // for epilogue reloads

  // np's ||x||^2: 8 accumulators over stride-8 elements, fixed fold tree
  float sumx;
  {
    float rr[8];
#pragma unroll
    for (int j = 0; j < 8; ++j) rr[j] = SQ(xs[row][j]);
#pragma unroll
    for (int i = 8; i < 64; i += 8) {
#pragma unroll
      for (int j = 0; j < 8; ++j) rr[j] = __fadd_rn(rr[j], SQ(xs[row][i + j]));
    }
    sumx = __fadd_rn(
        __fadd_rn(__fadd_rn(rr[0], rr[1]), __fadd_rn(rr[2], rr[3])),
        __fadd_rn(__fadd_rn(rr[4], rr[5]), __fadd_rn(rr[6], rr[7])));
  }

  // dist[c] = (sumx - 2*mm[c]) + sk[c]; mm = sequential-FMA dot over d=0..63
  float best = 3.402823466e38f;
  int bidx = 0;
  const int c0 = q * (KK / 4);
  for (int cc = 0; cc < KK / 4; cc += 2) {
    const int cA = c0 + cc;
    const int cB = cA + 1;
    const float4* kpA = (const float4*)(k + (size_t)cA * DD);
    const float4* kpB = kpA + 16;
    float aA = 0.f, aB = 0.f;
#pragma unroll
    for (int i = 0; i < 16; ++i) {
      const float4 xv = *(const float4*)&xs[row][4 * i];  // ds_read_b128
      const float4 kvA = kpA[i];
      const float4 kvB = kpB[i];
      aA = fmaf(xv.x, kvA.x, aA);
      aB = fmaf(xv.x, kvB.x, aB);
      aA = fmaf(xv.y, kvA.y, aA);
      aB = fmaf(xv.y, kvB.y, aB);
      aA = fmaf(xv.z, kvA.z, aA);
      aB = fmaf(xv.z, kvB.z, aB);
      aA = fmaf(xv.w, kvA.w, aA);
      aB = fmaf(xv.w, kvB.w, aB);
    }
    const float dA = __fadd_rn(__fsub_rn(sumx, __fmul_rn(2.0f, aA)), sk[cA]);
    const float dB = __fadd_rn(__fsub_rn(sumx, __fmul_rn(2.0f, aB)), sk[cB]);
    if (dA < best) { best = dA; bidx = cA; }   // strict < -> first index wins
    if (dB < best) { best = dB; bidx = cB; }
  }

  // combine 4 quarters; tie -> lowest index (matches np.argmin)
  {
    float ov = __shfl_xor(best, 16);
    int oi = __shfl_xor(bidx, 16);
    if (ov < best || (ov == best && oi < bidx)) { best = ov; bidx = oi; }
    ov = __shfl_xor(best, 32);
    oi = __shfl_xor(bidx, 32);
    if (ov < best || (ov == best && oi < bidx)) { best = ov; bidx = oi; }
  }

  if (q == 0) {
    out_codes[R0 + r] = (float)bidx;
    atomicAdd(&cnt_acc[bidx], 1.0f);
  }

  // epilogue: lane (q,r) handles d = 4*dg + q (x reloaded; L1/L2-hot)
  float csum = 0.f;
  const float* krow = k + (size_t)bidx * DD;
  float* xd_base = out_xd + (size_t)n * (DD * TT) + t;
#pragma unroll
  for (int dg = 0; dg < 16; ++dg) {
    const int d = dg * 4 + q;
    const float xq = krow[d];
    const float xv = xp[(size_t)d * TT];
    const float diff = __fsub_rn(xq, xv);
    xd_base[(size_t)d * TT] = __fadd_rn(xv, diff);
    csum = fmaf(diff, diff, csum);
    atomicAdd(&sum_acc[(size_t)bidx * DD + d], xv);
  }

#pragma unroll
  for (int off = 32; off >= 1; off >>= 1) csum += __shfl_xor(csum, off);
  if (lane == 0) atomicAdd(commit_acc, csum);
}

// ---------------- finalize: EMA buffers, k_new, commit mean ----------------
__global__ __launch_bounds__(256) void vq_finalize(
    const float* __restrict__ k, const float* __restrict__ k_sum,
    const float* __restrict__ k_elem, const float* __restrict__ cnt_raw,
    float* __restrict__ out_commit, float* __restrict__ out_knew,
    float* __restrict__ out_ksum, float* __restrict__ out_kelem) {
  const int i = blockIdx.x * 256 + threadIdx.x;
  if (i == 0) {
    out_commit[0] = out_commit[0] / 4194304.0f;
  }
  if (i < KK * DD) {
    const int c = i >> 6;
    const float cnt = cnt_raw[c];
    const float ke_n = __fadd_rn(__fmul_rn(0.99f, k_elem[c]), __fmul_rn(0.01f, cnt));
    const float s_raw = out_ksum[i];
    const float ks_n = __fadd_rn(__fmul_rn(0.99f, k_sum[i]), __fmul_rn(0.01f, s_raw));
    out_ksum[i] = ks_n;
    out_knew[i] = (ke_n >= 1.0f) ? (ks_n / ke_n) : k[i];
    if ((i & 63) == 0) out_kelem[c] = ke_n;
  }
}

extern "C" void kernel_launch(void* const* d_in, const int* in_sizes, int n_in,
                              void* d_out, int out_size, void* d_ws, size_t ws_size,
                              hipStream_t stream) {
  const float* x = (const float*)d_in[0];
  const float* k = (const float*)d_in[1];
  const float* k_sum = (const float*)d_in[2];
  const float* k_elem = (const float*)d_in[3];

  float* out = (float*)d_out;
  float* out_xd = out;
  float* out_codes = out + OFF_CODES;
  float* out_commit = out + OFF_COMMIT;
  float* out_knew = out + OFF_KNEW;
  float* out_ksum = out + OFF_KSUM;    // raw sum accumulator, finalized in place
  float* out_kelem = out + OFF_KELEM;

  char* ws = (char*)d_ws;
  float* sk = (float*)ws;              // 8 KB
  float* cnt_raw = (float*)(ws + 8192);

  hipMemsetAsync(out_ksum, 0, (size_t)KK * DD * sizeof(float), stream);
  hipMemsetAsync(cnt_raw, 0, (size_t)KK * sizeof(float), stream);
  hipMemsetAsync(out_commit, 0, sizeof(float), stream);

  vq_prep<<<(KK + 255) / 256, 256, 0, stream>>>(k, sk);

  vq_main<<<NTROWS / 64, 256, 0, stream>>>(x, k, sk, out_xd, out_codes,
                                           out_commit, out_ksum, cnt_raw);

  vq_finalize<<<(KK * DD + 255) / 256, 256, 0, stream>>>(
      k, k_sum, k_elem, cnt_raw, out_commit, out_knew, out_ksum, out_kelem);
}

// Round 8
// 1053.414 us; speedup vs baseline: 1.0897x; 1.0167x over previous
//
#include <hip/hip_runtime.h>

#define DD 64
#define TT 8192
#define KK 2048
#define NTROWS 65536

// d_out layout (float offsets), matching reference return order:
// xd[8*64*8192] | codes[65536] | commit[1] | k_new[131072] | k_sum_n[131072] | k_elem_n[2048]
#define OFF_CODES  4194304ull
#define OFF_COMMIT 4259840ull
#define OFF_KNEW   4259841ull
#define OFF_KSUM   4390913ull
#define OFF_KELEM  4521985ull

#define SQ(a) __fmul_rn((a), (a))

// ---------------- prep: sk[c] = np.sum(k[c]*k[c]) in replicated fp32 ----------
__global__ __launch_bounds__(256) void vq_prep(const float* __restrict__ k,
                                               float* __restrict__ sk) {
  int c = blockIdx.x * 256 + threadIdx.x;
  if (c < KK) {
    const float* v = k + (size_t)c * DD;
    float r[8];
#pragma unroll
    for (int j = 0; j < 8; ++j) r[j] = SQ(v[j]);
#pragma unroll
    for (int i = 8; i < 64; i += 8) {
#pragma unroll
      for (int j = 0; j < 8; ++j) r[j] = __fadd_rn(r[j], SQ(v[i + j]));
    }
    sk[c] = __fadd_rn(
        __fadd_rn(__fadd_rn(r[0], r[1]), __fadd_rn(r[2], r[3])),
        __fadd_rn(__fadd_rn(r[4], r[5]), __fadd_rn(r[6], r[7])));
  }
}

// ---------------- argmin: wave-uniform k, lane = row ----------------
// Block = 64 rows x 4 waves; wave w scans code quarter w for all 64 rows.
// k addresses are wave-uniform (readfirstlane) -> scalar/SMEM path, no
// per-lane k VGPR pressure. x in LDS [64][65] (pad 65 -> 2-way banks, free).
// 4 codes interleaved per x-chunk: 4 independent sequential FMA chains,
// each bit-identical to the validated round-3 per-code chain.
__global__ __launch_bounds__(256) void vq_argmin(
    const float* __restrict__ x, const float* __restrict__ k,
    const float* __restrict__ sk, float* __restrict__ out_codes) {
  __shared__ float xs[64][65];       // 16640 B
  __shared__ float bv[4][64];
  __shared__ int bi[4][64];

  const int lane = threadIdx.x & 63;       // row within block
  const int wv = threadIdx.x >> 6;         // code quarter

  const int R0 = blockIdx.x * 64;
  const int n = R0 >> 13;                  // T = 8192
  const int t0 = R0 & (TT - 1);

  // ---- stage 64 rows into LDS, coalesced ----
  {
    const float* xb = x + (size_t)n * (DD * TT) + t0;
    const int tt = threadIdx.x & 63;
    const int dq = threadIdx.x >> 6;       // 0..3
#pragma unroll
    for (int chunk = 0; chunk < 16; ++chunk) {
      const int d = chunk * 4 + dq;
      xs[tt][d] = xb[(size_t)d * TT + tt];
    }
  }
  __syncthreads();

  // np's ||x||^2: 8 accumulators over stride-8 elements, fixed fold tree
  float sumx;
  {
    float rr[8];
#pragma unroll
    for (int j = 0; j < 8; ++j) rr[j] = SQ(xs[lane][j]);
#pragma unroll
    for (int i = 8; i < 64; i += 8) {
#pragma unroll
      for (int j = 0; j < 8; ++j) rr[j] = __fadd_rn(rr[j], SQ(xs[lane][i + j]));
    }
    sumx = __fadd_rn(
        __fadd_rn(__fadd_rn(rr[0], rr[1]), __fadd_rn(rr[2], rr[3])),
        __fadd_rn(__fadd_rn(rr[4], rr[5]), __fadd_rn(rr[6], rr[7])));
  }

  // wave-uniform code base (force SGPR)
  const int qbase = __builtin_amdgcn_readfirstlane(wv) * (KK / 4);

  float best = 3.402823466e38f;
  int bidx = 0;
  for (int cc = 0; cc < KK / 4; cc += 4) {
    const int c0 = qbase + cc;
    const float4* kp0 = (const float4*)(k + (size_t)c0 * DD);        // uniform
    const float4* kp1 = kp0 + 16;
    const float4* kp2 = kp0 + 32;
    const float4* kp3 = kp0 + 48;
    float a0 = 0.f, a1 = 0.f, a2 = 0.f, a3 = 0.f;
#pragma unroll
    for (int i = 0; i < 16; ++i) {
      const float4 xv = *(const float4*)&xs[lane][4 * i];  // one read, 4 codes
      const float4 kv0 = kp0[i];
      const float4 kv1 = kp1[i];
      const float4 kv2 = kp2[i];
      const float4 kv3 = kp3[i];
      a0 = fmaf(xv.x, kv0.x, a0);
      a1 = fmaf(xv.x, kv1.x, a1);
      a2 = fmaf(xv.x, kv2.x, a2);
      a3 = fmaf(xv.x, kv3.x, a3);
      a0 = fmaf(xv.y, kv0.y, a0);
      a1 = fmaf(xv.y, kv1.y, a1);
      a2 = fmaf(xv.y, kv2.y, a2);
      a3 = fmaf(xv.y, kv3.y, a3);
      a0 = fmaf(xv.z, kv0.z, a0);
      a1 = fmaf(xv.z, kv1.z, a1);
      a2 = fmaf(xv.z, kv2.z, a2);
      a3 = fmaf(xv.z, kv3.z, a3);
      a0 = fmaf(xv.w, kv0.w, a0);
      a1 = fmaf(xv.w, kv1.w, a1);
      a2 = fmaf(xv.w, kv2.w, a2);
      a3 = fmaf(xv.w, kv3.w, a3);
    }
    const float d0 = __fadd_rn(__fsub_rn(sumx, __fmul_rn(2.0f, a0)), sk[c0]);
    const float d1 = __fadd_rn(__fsub_rn(sumx, __fmul_rn(2.0f, a1)), sk[c0 + 1]);
    const float d2 = __fadd_rn(__fsub_rn(sumx, __fmul_rn(2.0f, a2)), sk[c0 + 2]);
    const float d3 = __fadd_rn(__fsub_rn(sumx, __fmul_rn(2.0f, a3)), sk[c0 + 3]);
    if (d0 < best) { best = d0; bidx = c0; }   // strict < -> first index wins
    if (d1 < best) { best = d1; bidx = c0 + 1; }
    if (d2 < best) { best = d2; bidx = c0 + 2; }
    if (d3 < best) { best = d3; bidx = c0 + 3; }
  }

  // cross-wave combine: quarters ascending, strict < keeps lowest index
  bv[wv][lane] = best;
  bi[wv][lane] = bidx;
  __syncthreads();
  if (threadIdx.x < 64) {
    float v = bv[0][threadIdx.x];
    int ii = bi[0][threadIdx.x];
#pragma unroll
    for (int qq = 1; qq < 4; ++qq) {
      const float ov = bv[qq][threadIdx.x];
      if (ov < v) { v = ov; ii = bi[qq][threadIdx.x]; }
    }
    out_codes[R0 + threadIdx.x] = (float)ii;
  }
}

// ---------------- epilogue: gather, xd, commit, EMA scatter ----------------
__global__ __launch_bounds__(256) void vq_epi(
    const float* __restrict__ x, const float* __restrict__ k,
    const float* __restrict__ codes_f, float* __restrict__ out_xd,
    float* __restrict__ commit_acc, float* __restrict__ sum_acc,
    float* __restrict__ cnt_acc) {
  const int row = blockIdx.x * 256 + threadIdx.x;
  const int n = row >> 13;
  const int t = row & (TT - 1);
  const int code = (int)codes_f[row];

  const float* xp = x + (size_t)n * (DD * TT) + t;
  float* xd_base = out_xd + (size_t)n * (DD * TT) + t;
  const float4* kr = (const float4*)(k + (size_t)code * DD);

  float csum = 0.f;
#pragma unroll
  for (int dg = 0; dg < 16; ++dg) {
    const float4 kq = kr[dg];                 // scattered, L2-hot
#pragma unroll
    for (int j = 0; j < 4; ++j) {
      const int d = dg * 4 + j;
      const float xq = (j == 0) ? kq.x : (j == 1) ? kq.y : (j == 2) ? kq.z : kq.w;
      const float xv = xp[(size_t)d * TT];    // coalesced across threads
      const float diff = __fsub_rn(xq, xv);
      xd_base[(size_t)d * TT] = __fadd_rn(xv, diff);
      csum = fmaf(diff, diff, csum);
      atomicAdd(&sum_acc[(size_t)code * DD + d], xv);
    }
  }
  atomicAdd(&cnt_acc[code], 1.0f);

  // one commit atomic per wave
#pragma unroll
  for (int off = 32; off >= 1; off >>= 1) csum += __shfl_xor(csum, off);
  if ((threadIdx.x & 63) == 0) atomicAdd(commit_acc, csum);
}

// ---------------- finalize: EMA buffers, k_new, commit mean ----------------
__global__ __launch_bounds__(256) void vq_finalize(
    const float* __restrict__ k, const float* __restrict__ k_sum,
    const float* __restrict__ k_elem, const float* __restrict__ cnt_raw,
    float* __restrict__ out_commit, float* __restrict__ out_knew,
    float* __restrict__ out_ksum, float* __restrict__ out_kelem) {
  const int i = blockIdx.x * 256 + threadIdx.x;
  if (i == 0) {
    out_commit[0] = out_commit[0] / 4194304.0f;
  }
  if (i < KK * DD) {
    const int c = i >> 6;
    const float cnt = cnt_raw[c];
    const float ke_n = __fadd_rn(__fmul_rn(0.99f, k_elem[c]), __fmul_rn(0.01f, cnt));
    const float s_raw = out_ksum[i];
    const float ks_n = __fadd_rn(__fmul_rn(0.99f, k_sum[i]), __fmul_rn(0.01f, s_raw));
    out_ksum[i] = ks_n;
    out_knew[i] = (ke_n >= 1.0f) ? (ks_n / ke_n) : k[i];
    if ((i & 63) == 0) out_kelem[c] = ke_n;
  }
}

extern "C" void kernel_launch(void* const* d_in, const int* in_sizes, int n_in,
                              void* d_out, int out_size, void* d_ws, size_t ws_size,
                              hipStream_t stream) {
  const float* x = (const float*)d_in[0];
  const float* k = (const float*)d_in[1];
  const float* k_sum = (const float*)d_in[2];
  const float* k_elem = (const float*)d_in[3];

  float* out = (float*)d_out;
  float* out_xd = out;
  float* out_codes = out + OFF_CODES;
  float* out_commit = out + OFF_COMMIT;
  float* out_knew = out + OFF_KNEW;
  float* out_ksum = out + OFF_KSUM;    // raw sum accumulator, finalized in place
  float* out_kelem = out + OFF_KELEM;

  char* ws = (char*)d_ws;
  float* sk = (float*)ws;              // 8 KB
  float* cnt_raw = (float*)(ws + 8192);

  hipMemsetAsync(out_ksum, 0, (size_t)KK * DD * sizeof(float), stream);
  hipMemsetAsync(cnt_raw, 0, (size_t)KK * sizeof(float), stream);
  hipMemsetAsync(out_commit, 0, sizeof(float), stream);

  vq_prep<<<(KK + 255) / 256, 256, 0, stream>>>(k, sk);

  vq_argmin<<<NTROWS / 64, 256, 0, stream>>>(x, k, sk, out_codes);

  vq_epi<<<NTROWS / 256, 256, 0, stream>>>(x, k, out_codes, out_xd,
                                           out_commit, out_ksum, cnt_raw);

  vq_finalize<<<(KK * DD + 255) / 256, 256, 0, stream>>>(
      k, k_sum, k_elem, cnt_raw, out_commit, out_knew, out_ksum, out_kelem);
}